// Round 1
// baseline (253.402 us; speedup 1.0000x reference)
//
#include <hip/hip_runtime.h>
#include <stdint.h>

// MST on 128x256 grid, B=4 batches, Boruvka with (weight, eid) total order.
// Weights: f32 L2 over 64 channels, sequential accumulation, NO fma
// contraction (must bit-match numpy/XLA reference since output is a
// compacted edge list — one flipped comparison shifts the whole tail).

#define HH 128
#define WW 256
#define NN (HH*WW)          // 32768
#define RE ((HH-1)*WW)      // 32512 row edges
#define CE (HH*(WW-1))      // 32640 col edges
#define EE (RE+CE)          // 65152
#define BATCH 4
#define CH 64
#define ROUNDS 16

typedef unsigned long long u64;
typedef unsigned int u32;

__device__ __forceinline__ void edge_uv(int e, int& u, int& v) {
    if (e < RE) { u = e; v = e + WW; }          // row edge: (i,j)-(i+1,j), e = i*W+j
    else {                                      // col edge: (i,j)-(i,j+1)
        int ec = e - RE;
        int i = ec / (WW - 1);
        int j = ec - i * (WW - 1);
        u = i * WW + j; v = u + 1;
    }
}

// ---- weights -> packed keys: key = (bits(w)<<32) | eid  (w >= 0 so bit order == float order)
__global__ void k_keys(const float* __restrict__ g, u64* __restrict__ key) {
    int t = blockIdx.x * blockDim.x + threadIdx.x;
    if (t >= BATCH * EE) return;
    int b = t / EE, e = t - b * EE;
    int u, v; edge_uv(e, u, v);
    const float* gb = g + (size_t)b * CH * NN;
    float acc = 0.0f;
    #pragma unroll 8
    for (int c = 0; c < CH; ++c) {
        float d = gb[(size_t)c * NN + u] - gb[(size_t)c * NN + v];
        acc = __fadd_rn(acc, __fmul_rn(d, d));   // forbid fma contraction
    }
    float w = sqrtf(acc);                        // correctly-rounded (no fast-math)
    key[t] = ((u64)__float_as_uint(w) << 32) | (u32)e;
}

// ---- init: label[n]=n, selected=0, best=MAX
__global__ void k_init(u32* __restrict__ label, u32* __restrict__ sel, u64* __restrict__ best) {
    int t = blockIdx.x * blockDim.x + threadIdx.x;
    if (t < BATCH * NN) { label[t] = (u32)(t & (NN - 1)); best[t] = ~0ull; }
    if (t < BATCH * EE) sel[t] = 0u;
}

// ---- per-edge scatter-min into both endpoint components
__global__ void k_edgemin(const u64* __restrict__ key, const u32* __restrict__ label,
                          u64* __restrict__ best) {
    int t = blockIdx.x * blockDim.x + threadIdx.x;
    if (t >= BATCH * EE) return;
    int b = t / EE, e = t - b * EE;
    int u, v; edge_uv(e, u, v);
    const u32* lab = label + (size_t)b * NN;
    u32 cu = lab[u], cv = lab[v];
    if (cu == cv) return;
    u64 k = key[t];
    u64* bb = best + (size_t)b * NN;
    atomicMin(bb + cu, k);
    atomicMin(bb + cv, k);
}

// ---- hook: succ_raw from best edges; mark selected
__global__ void k_hook(const u64* __restrict__ best, const u32* __restrict__ label,
                       u32* __restrict__ sraw, u32* __restrict__ sel) {
    int t = blockIdx.x * blockDim.x + threadIdx.x;
    if (t >= BATCH * NN) return;
    int b = t >> 15, n = t & (NN - 1);
    u64 bk = best[t];
    u32 s = (u32)n;
    if (bk != ~0ull) {
        int e = (int)(u32)bk;
        int u, v; edge_uv(e, u, v);
        const u32* lab = label + (size_t)b * NN;
        u32 ou = lab[u], ov = lab[v];
        s = (ou == (u32)n) ? ov : ou;
        sel[(size_t)b * EE + e] = 1u;            // benign race: same value
    }
    sraw[t] = s;
}

// ---- break 2-cycles (the only cycles under a strict total order)
__global__ void k_2cyc(const u32* __restrict__ sraw, u32* __restrict__ succ) {
    int t = blockIdx.x * blockDim.x + threadIdx.x;
    if (t >= BATCH * NN) return;
    int b = t >> 15, n = t & (NN - 1);
    const u32* s = sraw + (size_t)b * NN;
    u32 m = s[n];
    u32 o = m;
    if (s[m] == (u32)n && (u32)n < m) o = (u32)n;
    succ[t] = o;
}

// ---- relabel to roots (exact chase == reference's 16 pointer-doublings) + reset best
__global__ void k_relabel(const u32* __restrict__ succ, u32* __restrict__ label,
                          u64* __restrict__ best) {
    int t = blockIdx.x * blockDim.x + threadIdx.x;
    if (t >= BATCH * NN) return;
    int b = t >> 15;
    const u32* s = succ + (size_t)b * NN;
    u32 r = label[t];
    u32 nx = s[r];
    while (nx != r) { r = nx; nx = s[r]; }
    label[t] = r;
    best[t] = ~0ull;                             // reset for next round
}

// ---- stable compaction by eid: one block per batch, ballot scan
__global__ __launch_bounds__(1024) void k_compact(const u32* __restrict__ sel,
                                                  int* __restrict__ out) {
    int b = blockIdx.x;
    const u32* sb = sel + (size_t)b * EE;
    int* ob = out + (size_t)b * (NN - 1) * 2;
    __shared__ u32 woff[16];
    __shared__ u32 base;
    if (threadIdx.x == 0) base = 0;
    __syncthreads();
    int lane = threadIdx.x & 63, wid = threadIdx.x >> 6;
    for (int start = 0; start < EE; start += 1024) {
        int e = start + (int)threadIdx.x;
        bool f = (e < EE) && (sb[e] != 0u);
        u64 m = __ballot(f);
        u32 pre = __popcll(m & ((1ull << lane) - 1));
        if (lane == 0) woff[wid] = (u32)__popcll(m);
        __syncthreads();
        if (threadIdx.x == 0) {
            u32 acc = base;
            for (int i = 0; i < 16; ++i) { u32 tt = woff[i]; woff[i] = acc; acc += tt; }
            base = acc;
        }
        __syncthreads();
        if (f) {
            u32 pos = woff[wid] + pre;
            int u, v; edge_uv(e, u, v);
            ob[(size_t)pos * 2]     = u;
            ob[(size_t)pos * 2 + 1] = v;
        }
        __syncthreads();
    }
}

extern "C" void kernel_launch(void* const* d_in, const int* in_sizes, int n_in,
                              void* d_out, int out_size, void* d_ws, size_t ws_size,
                              hipStream_t stream) {
    const float* g = (const float*)d_in[0];
    int* out = (int*)d_out;
    char* ws = (char*)d_ws;

    // workspace layout (~5.7 MB total)
    u64* key   = (u64*)ws;                                   // B*E*8 = 2084864
    u64* best  = (u64*)(ws + (size_t)BATCH * EE * 8);        // B*N*8 = 1048576
    u32* label = (u32*)(ws + (size_t)BATCH * EE * 8 + (size_t)BATCH * NN * 8);
    u32* sraw  = label + (size_t)BATCH * NN;
    u32* succ  = sraw  + (size_t)BATCH * NN;
    u32* sel   = succ  + (size_t)BATCH * NN;                 // B*E*4

    dim3 blk(256);
    int gE = (BATCH * EE + 255) / 256;
    int gN = (BATCH * NN + 255) / 256;

    k_keys<<<gE, blk, 0, stream>>>(g, key);
    k_init<<<gE, blk, 0, stream>>>(label, sel, best);
    for (int r = 0; r < ROUNDS; ++r) {
        k_edgemin<<<gE, blk, 0, stream>>>(key, label, best);
        k_hook   <<<gN, blk, 0, stream>>>(best, label, sraw, sel);
        k_2cyc   <<<gN, blk, 0, stream>>>(sraw, succ);
        k_relabel<<<gN, blk, 0, stream>>>(succ, label, best);
    }
    k_compact<<<BATCH, dim3(1024), 0, stream>>>(sel, out);
}

// Round 2
// 162.758 us; speedup vs baseline: 1.5569x; 1.5569x over previous
//
#include <hip/hip_runtime.h>
#include <stdint.h>

// MST on 128x256 grid, B=4 batches, Boruvka with (weight, eid) total order.
// Round fused to 2 kernels: edgemin(+relabel-chase), hook(+2cycle+reset-other).
// Weights: f32 L2 over 64 channels, sequential accumulation, NO fma
// contraction (bit-matches numpy/XLA reference — output is a compacted edge
// list, one flipped comparison shifts the whole tail).

#define HH 128
#define WW 256
#define NN (HH*WW)          // 32768
#define RE ((HH-1)*WW)      // 32512 row edges
#define CE (HH*(WW-1))      // 32640 col edges
#define EE (RE+CE)          // 65152
#define BATCH 4
#define CH 64
#define ROUNDS 15           // components at least halve per round; 2^15 = N

typedef unsigned long long u64;
typedef unsigned int u32;

__device__ __forceinline__ void edge_uv(int e, int& u, int& v) {
    if (e < RE) { u = e; v = e + WW; }          // row edge: (i,j)-(i+1,j)
    else {                                      // col edge: (i,j)-(i,j+1)
        int ec = e - RE;
        int i = ec / (WW - 1);
        int j = ec - i * (WW - 1);
        u = i * WW + j; v = u + 1;
    }
}

// ---- weights (bit-exact vs reference): keyw = float bits of w (w>=0)
__global__ void k_keys(const float* __restrict__ g, u32* __restrict__ keyw) {
    int t = blockIdx.x * blockDim.x + threadIdx.x;
    if (t >= BATCH * EE) return;
    int b = t / EE, e = t - b * EE;
    int u, v; edge_uv(e, u, v);
    const float* gb = g + (size_t)b * CH * NN;
    float acc = 0.0f;
    #pragma unroll 8
    for (int c = 0; c < CH; ++c) {
        float d = gb[(size_t)c * NN + u] - gb[(size_t)c * NN + v];
        acc = __fadd_rn(acc, __fmul_rn(d, d));   // forbid fma contraction
    }
    keyw[t] = __float_as_uint(sqrtf(acc));
}

// ---- init: label=succ=identity, bestA=bestB=MAX, sel=0, flags=0
__global__ void k_init(u32* __restrict__ label, u32* __restrict__ succ,
                       u64* __restrict__ bestA, u64* __restrict__ bestB,
                       u32* __restrict__ sel, int* __restrict__ flags) {
    int t = blockIdx.x * blockDim.x + threadIdx.x;
    if (t < BATCH * NN) {
        u32 n = (u32)(t & (NN - 1));
        label[t] = n; succ[t] = n;
        bestA[t] = ~0ull; bestB[t] = ~0ull;
    }
    if (t < BATCH * EE) sel[t] = 0u;
    if (t < ROUNDS) flags[t] = 0;
}

// ---- per-edge: chase both endpoints to roots (via prev round's succ),
//      write roots back to label (benign same-value race), scatter-min.
__global__ void k_edgemin(const u32* __restrict__ keyw, const u32* __restrict__ succ,
                          u32* __restrict__ label, u64* __restrict__ best,
                          const int* __restrict__ flags, int r) {
    if (r > 0 && flags[r - 1] == 0) return;      // converged: nothing changes
    int t = blockIdx.x * blockDim.x + threadIdx.x;
    if (t >= BATCH * EE) return;
    int b = t / EE, e = t - b * EE;
    int u, v; edge_uv(e, u, v);
    const u32* sb = succ + (size_t)b * NN;
    u32* lab = label + (size_t)b * NN;
    u32 ru = lab[u]; { u32 nx = sb[ru]; while (nx != ru) { ru = nx; nx = sb[ru]; } }
    u32 rv = lab[v]; { u32 nx = sb[rv]; while (nx != rv) { rv = nx; nx = sb[rv]; } }
    lab[u] = ru; lab[v] = rv;
    if (ru == rv) return;
    u64 k = ((u64)keyw[t] << 32) | (u32)e;
    u64* bb = best + (size_t)b * NN;
    atomicMin(bb + ru, k);
    atomicMin(bb + rv, k);
}

// ---- per-node: hook via best edge; 2-cycle iff both sides chose the SAME
//      edge (mutual min over the same cut => equal (w,eid) keys); mark sel;
//      reset the OTHER best buffer for next round; set activity flag.
__global__ void k_hook(const u64* __restrict__ best, u64* __restrict__ bestNext,
                       const u32* __restrict__ label, u32* __restrict__ succ,
                       u32* __restrict__ sel, int* __restrict__ flags, int r) {
    if (r > 0 && flags[r - 1] == 0) return;
    int t = blockIdx.x * blockDim.x + threadIdx.x;
    if (t >= BATCH * NN) return;
    int b = t >> 15, n = t & (NN - 1);
    u64 bk = best[t];
    u32 s = (u32)n;
    if (bk != ~0ull) {
        int e = (int)(u32)bk;
        int u, v; edge_uv(e, u, v);
        const u32* lab = label + (size_t)b * NN;
        u32 ou = lab[u], ov = lab[v];
        u32 o = (ou == (u32)n) ? ov : ou;
        u64 bko = best[(size_t)b * NN + o];
        s = ((u32)bko == (u32)bk && (u32)n < o) ? (u32)n : o;
        sel[(size_t)b * EE + e] = 1u;            // benign race: same value
        flags[r] = 1;                            // benign race: same value
    }
    succ[t] = s;
    bestNext[t] = ~0ull;
}

// ---- compaction: 64 chunks x 1024 edges per batch
__global__ __launch_bounds__(1024) void k_ccount(const u32* __restrict__ sel,
                                                 u32* __restrict__ ccnt) {
    int blk = blockIdx.x;                        // b*64 + chunk
    int b = blk >> 6, ch = blk & 63;
    int e = ch * 1024 + (int)threadIdx.x;
    bool f = (e < EE) && (sel[(size_t)b * EE + e] != 0u);
    u64 m = __ballot(f);
    __shared__ u32 wc[16];
    int lane = threadIdx.x & 63, wid = threadIdx.x >> 6;
    if (lane == 0) wc[wid] = (u32)__popcll(m);
    __syncthreads();
    if (threadIdx.x == 0) {
        u32 s = 0;
        #pragma unroll
        for (int i = 0; i < 16; ++i) s += wc[i];
        ccnt[blk] = s;
    }
}

// one block, 256 threads = 4 waves; wave b scans batch b's 64 chunk counts
__global__ void k_cscan(const u32* __restrict__ ccnt, u32* __restrict__ cbase) {
    int lane = threadIdx.x & 63, b = threadIdx.x >> 6;
    u32 v = ccnt[b * 64 + lane];
    u32 incl = v;
    #pragma unroll
    for (int d = 1; d < 64; d <<= 1) {
        u32 tt = __shfl_up(incl, d, 64);
        if (lane >= d) incl += tt;
    }
    cbase[b * 64 + lane] = incl - v;             // exclusive
}

__global__ __launch_bounds__(1024) void k_cwrite(const u32* __restrict__ sel,
                                                 const u32* __restrict__ cbase,
                                                 int* __restrict__ out) {
    int blk = blockIdx.x;
    int b = blk >> 6, ch = blk & 63;
    int e = ch * 1024 + (int)threadIdx.x;
    bool f = (e < EE) && (sel[(size_t)b * EE + e] != 0u);
    u64 m = __ballot(f);
    int lane = threadIdx.x & 63, wid = threadIdx.x >> 6;
    __shared__ u32 woff[16];
    if (lane == 0) woff[wid] = (u32)__popcll(m);
    __syncthreads();
    if (threadIdx.x == 0) {
        u32 acc = cbase[blk];
        #pragma unroll
        for (int i = 0; i < 16; ++i) { u32 tt = woff[i]; woff[i] = acc; acc += tt; }
    }
    __syncthreads();
    if (f) {
        u32 pos = woff[wid] + (u32)__popcll(m & ((1ull << lane) - 1));
        int u, v; edge_uv(e, u, v);
        int* ob = out + (size_t)b * (NN - 1) * 2;
        ob[(size_t)pos * 2]     = u;
        ob[(size_t)pos * 2 + 1] = v;
    }
}

extern "C" void kernel_launch(void* const* d_in, const int* in_sizes, int n_in,
                              void* d_out, int out_size, void* d_ws, size_t ws_size,
                              hipStream_t stream) {
    const float* g = (const float*)d_in[0];
    int* out = (int*)d_out;
    char* ws = (char*)d_ws;

    // workspace layout (~5.2 MB), 8B-aligned blocks first
    u64* bestA = (u64*)ws;                                   // B*N*8
    u64* bestB = bestA + (size_t)BATCH * NN;                 // B*N*8
    u32* keyw  = (u32*)(bestB + (size_t)BATCH * NN);         // B*E*4
    u32* label = keyw + (size_t)BATCH * EE;                  // B*N*4
    u32* succ  = label + (size_t)BATCH * NN;                 // B*N*4
    u32* sel   = succ + (size_t)BATCH * NN;                  // B*E*4
    u32* ccnt  = sel + (size_t)BATCH * EE;                   // 256*4
    u32* cbase = ccnt + 256;                                 // 256*4
    int* flags = (int*)(cbase + 256);                        // ROUNDS*4

    dim3 blk(256);
    int gE = (BATCH * EE + 255) / 256;
    int gN = (BATCH * NN + 255) / 256;

    k_keys<<<gE, blk, 0, stream>>>(g, keyw);
    k_init<<<gE, blk, 0, stream>>>(label, succ, bestA, bestB, sel, flags);
    for (int r = 0; r < ROUNDS; ++r) {
        u64* cur = (r & 1) ? bestB : bestA;
        u64* nxt = (r & 1) ? bestA : bestB;
        k_edgemin<<<gE, blk, 0, stream>>>(keyw, succ, label, cur, flags, r);
        k_hook   <<<gN, blk, 0, stream>>>(cur, nxt, label, succ, sel, flags, r);
    }
    k_ccount<<<256, dim3(1024), 0, stream>>>(sel, ccnt);
    k_cscan <<<1, dim3(256), 0, stream>>>(ccnt, cbase);
    k_cwrite<<<256, dim3(1024), 0, stream>>>(sel, cbase, out);
}